// Round 2
// 1541.715 us; speedup vs baseline: 1.3637x; 1.3637x over previous
//
#include <hip/hip_runtime.h>
#include <math.h>

#define DIM_K 7168
#define NE 256
#define NG 8
#define GSZ 32
#define TOPKN 8
#define TOPKG 4

constexpr int BM = 32;      // tokens per block
constexpr int BK = 16;      // k-chunk
constexpr int LDK = BK + 4; // LDS row stride (f32): 20 keeps float4 16B-alignment
                            // and spreads banks (gcd(20,32)=4 -> <=2 lanes/bank)

typedef __attribute__((ext_vector_type(4))) double dbl4;

// ---------------------------------------------------------------------------
// f64 MFMA GEMM. Numerics identical to the f64-FMA version (f64-accumulated
// logits, f64 sigmoid, RNE cast to f32); dot products on the f64 matrix pipe.
//
// FRAGMENT LAYOUTS for v_mfma_f64_16x16x4_f64 (NOT the standard gfx950 16x16
// C/D mapping!):
//   A[i][k]: i = lane&15, k = lane>>4        (standard)
//   B[k][j]: j = lane&15, k = lane>>4        (standard)
//   C/D[i][j]: j = lane&15, i = 4*reg + (lane>>4)   <-- REGISTER-MAJOR.
// CK's xdlops descriptor for mfma_f64_16x16x4 is group_size=1,
// num_groups_per_blk=4 (f32 16x16x4 is group_size=4, num_groups=1), i.e. the
// 4 acc regs stride rows by 4. Round-1 used row=4*(lane>>4)+reg, which is a
// within-16 row permutation: weights stayed plausible (passed), indices
// scrambled (absmax 253). This epilogue uses row = 4*reg + (lane>>4).
// ---------------------------------------------------------------------------
__global__ __launch_bounds__(256, 2)
void gemm_sigmoid_mfma_f64(const float* __restrict__ x,
                           const float* __restrict__ w,
                           float* __restrict__ scores)
{
    __shared__ float As[BM][LDK];   // x tile, row-major
    __shared__ float Bs[NE][LDK];   // W tile, row-major (B[k][e] = Bs[e][k])

    const int tid  = threadIdx.x;
    const int wave = tid >> 6;
    const int lane = tid & 63;
    const int m_blk = blockIdx.x * BM;

    const int l15 = lane & 15;
    const int lk  = lane >> 4;        // k-offset inside one mfma / row sub-idx
    const int e_base = wave * 64;     // wave's 64-expert slice

    const dbl4 zero = {0.0, 0.0, 0.0, 0.0};
    dbl4 acc[2][4];                   // [m-subtile][e-subtile], 64 VGPRs
#pragma unroll
    for (int i = 0; i < 2; ++i)
#pragma unroll
        for (int j = 0; j < 4; ++j) acc[i][j] = zero;

    // staging: A 32x16 f32 (128 float4, threads<128) + B 256x16 f32 (4 float4
    // per thread). Row-major in LDS -> float4 load + b128 write, no transpose.
    const int srow = tid >> 2;        // 0..63
    const int sc   = (tid & 3) * 4;   // f32 col within chunk

    const float* xa = x + (long)(m_blk + (srow & 31)) * DIM_K + sc;
    const float* wb = w + (long)srow * DIM_K + sc;

    float4 ra, rb0, rb1, rb2, rb3;
    if (tid < 128) ra = *(const float4*)xa;
    rb0 = *(const float4*)(wb);
    rb1 = *(const float4*)(wb + (long) 64 * DIM_K);
    rb2 = *(const float4*)(wb + (long)128 * DIM_K);
    rb3 = *(const float4*)(wb + (long)192 * DIM_K);

    for (int k0 = 0; k0 < DIM_K; k0 += BK) {
        // write previously-fetched chunk to LDS (prev compute done)
        if (tid < 128) *(float4*)&As[srow & 31][sc] = ra;
        *(float4*)&Bs[srow      ][sc] = rb0;
        *(float4*)&Bs[srow +  64][sc] = rb1;
        *(float4*)&Bs[srow + 128][sc] = rb2;
        *(float4*)&Bs[srow + 192][sc] = rb3;
        __syncthreads();

        // prefetch next chunk; latency hides under the 32 mfma below
        if (k0 + BK < DIM_K) {
            const int off = k0 + BK;
            if (tid < 128) ra = *(const float4*)(xa + off);
            rb0 = *(const float4*)(wb + off);
            rb1 = *(const float4*)(wb + off + (long) 64 * DIM_K);
            rb2 = *(const float4*)(wb + off + (long)128 * DIM_K);
            rb3 = *(const float4*)(wb + off + (long)192 * DIM_K);
        }

#pragma unroll
        for (int ks = 0; ks < BK; ks += 4) {
            const int kk = ks + lk;
            const double a0 = (double)As[l15     ][kk];
            const double a1 = (double)As[l15 + 16][kk];
            const double b0 = (double)Bs[e_base      + l15][kk];
            const double b1 = (double)Bs[e_base + 16 + l15][kk];
            const double b2 = (double)Bs[e_base + 32 + l15][kk];
            const double b3 = (double)Bs[e_base + 48 + l15][kk];
            acc[0][0] = __builtin_amdgcn_mfma_f64_16x16x4f64(a0, b0, acc[0][0], 0, 0, 0);
            acc[1][0] = __builtin_amdgcn_mfma_f64_16x16x4f64(a1, b0, acc[1][0], 0, 0, 0);
            acc[0][1] = __builtin_amdgcn_mfma_f64_16x16x4f64(a0, b1, acc[0][1], 0, 0, 0);
            acc[1][1] = __builtin_amdgcn_mfma_f64_16x16x4f64(a1, b1, acc[1][1], 0, 0, 0);
            acc[0][2] = __builtin_amdgcn_mfma_f64_16x16x4f64(a0, b2, acc[0][2], 0, 0, 0);
            acc[1][2] = __builtin_amdgcn_mfma_f64_16x16x4f64(a1, b2, acc[1][2], 0, 0, 0);
            acc[0][3] = __builtin_amdgcn_mfma_f64_16x16x4f64(a0, b3, acc[0][3], 0, 0, 0);
            acc[1][3] = __builtin_amdgcn_mfma_f64_16x16x4f64(a1, b3, acc[1][3], 0, 0, 0);
        }
        __syncthreads();
    }

    // epilogue: f64 sigmoid, RNE cast to f32.
    // f64-MFMA C/D row mapping: row = 4*reg + (lane>>4)  (register-major).
#pragma unroll
    for (int mi = 0; mi < 2; ++mi) {
#pragma unroll
        for (int j = 0; j < 4; ++j) {
#pragma unroll
            for (int r = 0; r < 4; ++r) {
                const long m = m_blk + mi * 16 + r * 4 + lk;
                const int  e = e_base + j * 16 + l15;
                scores[m * NE + e] = (float)(1.0 / (1.0 + exp(-acc[mi][j][r])));
            }
        }
    }
}

// np-faithful f32 routing (unchanged from the passing version). All
// comparisons on f32(score)+f32(bias) with a single f32 RNE add. Strict '>'
// scans = jax.lax.top_k semantics (descending, lowest index on ties).
__global__ __launch_bounds__(64)
void route_f32(const float* __restrict__ scores,
               const float* __restrict__ bias,
               float* __restrict__ out_w,
               float* __restrict__ out_i)
{
    __shared__ float srow[64][NE + 1];
    __shared__ float bsh[NE];

    const int tid = threadIdx.x;
    const long tok0 = (long)blockIdx.x * 64;

#pragma unroll
    for (int l = 0; l < 4; ++l) bsh[tid * 4 + l] = bias[tid * 4 + l];

    for (int l = 0; l < 64; ++l) {
        const float4 v = *(const float4*)(scores + (tok0 + l) * NE + tid * 4);
        srow[l][tid * 4 + 0] = v.x;
        srow[l][tid * 4 + 1] = v.y;
        srow[l][tid * 4 + 2] = v.z;
        srow[l][tid * 4 + 3] = v.w;
    }
    __syncthreads();

    float* row = srow[tid];

    // group score = top-2 sum of biased scores (f32 add, m1+m2 order = np)
    float gs[NG];
#pragma unroll
    for (int g = 0; g < NG; ++g) {
        float m1 = -3.0e38f, m2 = -3.0e38f;
        for (int j = 0; j < GSZ; ++j) {
            const int e = g * GSZ + j;
            const float v = __fadd_rn(row[e], bsh[e]);
            if (v > m1) { m2 = m1; m1 = v; }
            else if (v > m2) { m2 = v; }
        }
        gs[g] = __fadd_rn(m1, m2);
    }

    // top-4 groups (selection set only)
    unsigned keep = 0;
#pragma unroll
    for (int r = 0; r < TOPKG; ++r) {
        float best = -3.0e38f; int bg = 0;
        for (int g = 0; g < NG; ++g)
            if (!((keep >> g) & 1u) && gs[g] > best) { best = gs[g]; bg = g; }
        keep |= 1u << bg;
    }

    // top-8 experts over kept groups by biased f32 score
    float wv[TOPKN]; int iv[TOPKN];
    for (int r = 0; r < TOPKN; ++r) {
        float best = -3.0e38f; int bi = 0;
        for (int g = 0; g < NG; ++g) {
            if (!((keep >> g) & 1u)) continue;
            for (int j = 0; j < GSZ; ++j) {
                const int e = g * GSZ + j;
                const float v = __fadd_rn(row[e], bsh[e]);
                if (v > best) { best = v; bi = e; }
            }
        }
        wv[r] = row[bi];        // ORIGINAL (un-biased) f32 sigmoid score
        iv[r] = bi;
        row[bi] = -3.0e38f;     // -3e38 + bias stays -3e38; never re-picked
    }

    // np n=8 pairwise-sum tree, then div-then-mul (elementwise, f32)
    const float s01 = __fadd_rn(wv[0], wv[1]);
    const float s23 = __fadd_rn(wv[2], wv[3]);
    const float s45 = __fadd_rn(wv[4], wv[5]);
    const float s67 = __fadd_rn(wv[6], wv[7]);
    const float wsum = __fadd_rn(__fadd_rn(s01, s23), __fadd_rn(s45, s67));

    const long token = tok0 + tid;
#pragma unroll
    for (int r = 0; r < TOPKN; ++r) {
        out_w[token * 8 + r] = __fmul_rn(__fdiv_rn(wv[r], wsum), 2.5f);
        out_i[token * 8 + r] = (float)iv[r];
    }
}

extern "C" void kernel_launch(void* const* d_in, const int* in_sizes, int n_in,
                              void* d_out, int out_size, void* d_ws, size_t ws_size,
                              hipStream_t stream)
{
    const float* x    = (const float*)d_in[0];
    const float* w    = (const float*)d_in[1];
    const float* bias = (const float*)d_in[2];
    float* out = (float*)d_out;
    const int T = in_sizes[0] / DIM_K;      // 16384
    float* scores = (float*)d_ws;           // T*256 f32 = 16.8 MB

    gemm_sigmoid_mfma_f64<<<dim3(T / BM), dim3(256), 0, stream>>>(x, w, scores);
    route_f32<<<dim3(T / 64), dim3(64), 0, stream>>>(scores, bias, out,
                                                     out + (long)T * TOPKN);
}

// Round 3
// 1535.187 us; speedup vs baseline: 1.3695x; 1.0043x over previous
//
#include <hip/hip_runtime.h>
#include <math.h>

#define DIM_K 7168
#define NE 256
#define NG 8
#define GSZ 32
#define TOPKN 8
#define TOPKG 4

constexpr int BM = 32;      // tokens per block
constexpr int BK = 16;      // k-chunk
constexpr int LDK = BK + 4; // LDS row stride (f32): 20 keeps float4 16B-alignment
                            // and spreads banks (gcd(20,32)=4 -> <=2 lanes/bank)

typedef __attribute__((ext_vector_type(4))) double dbl4;

// LDS: GEMM phase uses As[BM][LDK] + Bs[NE][LDK] = 23040 B.
// Route phase (after last k-loop barrier, As/Bs dead) reuses the same bytes as
// sc[BM][NE+1] (32x257 f32, +1 pad so thread-per-token scans are conflict-free)
// + bsh[NE]. Union size = 33920 B -> still 2 blocks/CU.
constexpr int GEMM_BYTES  = (BM * LDK + NE * LDK) * 4;
constexpr int ROUTE_BYTES = (BM * (NE + 1) + NE) * 4;
constexpr int SMEM_BYTES  = ROUTE_BYTES > GEMM_BYTES ? ROUTE_BYTES : GEMM_BYTES;

// ---------------------------------------------------------------------------
// Fused GEMM + sigmoid + routing.
// GEMM: f64-accumulated logits on the f64 matrix pipe, f64 sigmoid, RNE cast
// to f32 (same numerics as the passing R2 kernel).
// FRAGMENT LAYOUTS for v_mfma_f64_16x16x4_f64:
//   A[i][k]: i = lane&15, k = lane>>4
//   B[k][j]: j = lane&15, k = lane>>4
//   C/D[i][j]: j = lane&15, i = 4*reg + (lane>>4)   <-- REGISTER-MAJOR (f64
//   quirk, verified R2; standard 16x16 mapping is 4*(lane>>4)+reg).
// Routing: each block holds full 256-expert rows for its 32 tokens -> route
// in-block (threads 0..31, one token each), byte-identical scan code to the
// previously-passing route_f32. Kills the 16.8MB scores store + reload + the
// 1-wave/CU latency-bound second kernel (~410 us).
// ---------------------------------------------------------------------------
__global__ __launch_bounds__(256, 2)
void gemm_sigmoid_route(const float* __restrict__ x,
                        const float* __restrict__ w,
                        const float* __restrict__ bias,
                        float* __restrict__ out_w,
                        float* __restrict__ out_i)
{
    __shared__ __align__(16) char smem[SMEM_BYTES];
    float (*As)[LDK] = (float (*)[LDK])smem;                      // [BM][LDK]
    float (*Bs)[LDK] = (float (*)[LDK])(smem + BM * LDK * 4);     // [NE][LDK]

    const int tid  = threadIdx.x;
    const int wave = tid >> 6;
    const int lane = tid & 63;
    const int m_blk = blockIdx.x * BM;

    const int l15 = lane & 15;
    const int lk  = lane >> 4;        // k-offset inside one mfma / row sub-idx
    const int e_base = wave * 64;     // wave's 64-expert slice

    const dbl4 zero = {0.0, 0.0, 0.0, 0.0};
    dbl4 acc[2][4];                   // [m-subtile][e-subtile], 64 VGPRs
#pragma unroll
    for (int i = 0; i < 2; ++i)
#pragma unroll
        for (int j = 0; j < 4; ++j) acc[i][j] = zero;

    // staging: A 32x16 f32 (128 float4, threads<128) + B 256x16 f32 (4 float4
    // per thread). Row-major in LDS -> float4 load + b128 write, no transpose.
    const int srow = tid >> 2;        // 0..63
    const int sc4  = (tid & 3) * 4;   // f32 col within chunk

    const float* xa = x + (long)(m_blk + (srow & 31)) * DIM_K + sc4;
    const float* wb = w + (long)srow * DIM_K + sc4;

    float4 ra, rb0, rb1, rb2, rb3;
    if (tid < 128) ra = *(const float4*)xa;
    rb0 = *(const float4*)(wb);
    rb1 = *(const float4*)(wb + (long) 64 * DIM_K);
    rb2 = *(const float4*)(wb + (long)128 * DIM_K);
    rb3 = *(const float4*)(wb + (long)192 * DIM_K);

    for (int k0 = 0; k0 < DIM_K; k0 += BK) {
        // write previously-fetched chunk to LDS (prev compute done)
        if (tid < 128) *(float4*)&As[srow & 31][sc4] = ra;
        *(float4*)&Bs[srow      ][sc4] = rb0;
        *(float4*)&Bs[srow +  64][sc4] = rb1;
        *(float4*)&Bs[srow + 128][sc4] = rb2;
        *(float4*)&Bs[srow + 192][sc4] = rb3;
        __syncthreads();

        // prefetch next chunk; latency hides under the 32 mfma below
        if (k0 + BK < DIM_K) {
            const int off = k0 + BK;
            if (tid < 128) ra = *(const float4*)(xa + off);
            rb0 = *(const float4*)(wb + off);
            rb1 = *(const float4*)(wb + off + (long) 64 * DIM_K);
            rb2 = *(const float4*)(wb + off + (long)128 * DIM_K);
            rb3 = *(const float4*)(wb + off + (long)192 * DIM_K);
        }

#pragma unroll
        for (int ks = 0; ks < BK; ks += 4) {
            const int kk = ks + lk;
            const double a0 = (double)As[l15     ][kk];
            const double a1 = (double)As[l15 + 16][kk];
            const double b0 = (double)Bs[e_base      + l15][kk];
            const double b1 = (double)Bs[e_base + 16 + l15][kk];
            const double b2 = (double)Bs[e_base + 32 + l15][kk];
            const double b3 = (double)Bs[e_base + 48 + l15][kk];
            acc[0][0] = __builtin_amdgcn_mfma_f64_16x16x4f64(a0, b0, acc[0][0], 0, 0, 0);
            acc[1][0] = __builtin_amdgcn_mfma_f64_16x16x4f64(a1, b0, acc[1][0], 0, 0, 0);
            acc[0][1] = __builtin_amdgcn_mfma_f64_16x16x4f64(a0, b1, acc[0][1], 0, 0, 0);
            acc[1][1] = __builtin_amdgcn_mfma_f64_16x16x4f64(a1, b1, acc[1][1], 0, 0, 0);
            acc[0][2] = __builtin_amdgcn_mfma_f64_16x16x4f64(a0, b2, acc[0][2], 0, 0, 0);
            acc[1][2] = __builtin_amdgcn_mfma_f64_16x16x4f64(a1, b2, acc[1][2], 0, 0, 0);
            acc[0][3] = __builtin_amdgcn_mfma_f64_16x16x4f64(a0, b3, acc[0][3], 0, 0, 0);
            acc[1][3] = __builtin_amdgcn_mfma_f64_16x16x4f64(a1, b3, acc[1][3], 0, 0, 0);
        }
        __syncthreads();
    }
    // After this barrier As/Bs are dead -> repurpose LDS for routing.

    float (*sc)[NE + 1] = (float (*)[NE + 1])smem;                // [BM][257]
    float* bsh = (float*)(smem + BM * (NE + 1) * 4);              // [NE]

    // f64 sigmoid, RNE cast to f32, scattered to LDS score rows.
    // f64-MFMA C/D row mapping: row = 4*reg + (lane>>4)  (register-major).
#pragma unroll
    for (int mi = 0; mi < 2; ++mi) {
#pragma unroll
        for (int j = 0; j < 4; ++j) {
#pragma unroll
            for (int r = 0; r < 4; ++r) {
                const int m = mi * 16 + r * 4 + lk;
                const int e = e_base + j * 16 + l15;
                sc[m][e] = (float)(1.0 / (1.0 + exp(-acc[mi][j][r])));
            }
        }
    }
    if (tid < 64) {
        const float4 bv = *(const float4*)(bias + tid * 4);
        bsh[tid * 4 + 0] = bv.x;
        bsh[tid * 4 + 1] = bv.y;
        bsh[tid * 4 + 2] = bv.z;
        bsh[tid * 4 + 3] = bv.w;
    }
    __syncthreads();

    // np-faithful f32 routing, one thread per token (threads 0..31).
    // Identical scan order / __fadd_rn semantics to the passing route_f32.
    if (tid < BM) {
        float* row = sc[tid];

        // group score = top-2 sum of biased scores (f32 add, m1+m2 order = np)
        float gs[NG];
#pragma unroll
        for (int g = 0; g < NG; ++g) {
            float m1 = -3.0e38f, m2 = -3.0e38f;
            for (int j = 0; j < GSZ; ++j) {
                const int e = g * GSZ + j;
                const float v = __fadd_rn(row[e], bsh[e]);
                if (v > m1) { m2 = m1; m1 = v; }
                else if (v > m2) { m2 = v; }
            }
            gs[g] = __fadd_rn(m1, m2);
        }

        // top-4 groups (selection set only)
        unsigned keep = 0;
#pragma unroll
        for (int r = 0; r < TOPKG; ++r) {
            float best = -3.0e38f; int bg = 0;
            for (int g = 0; g < NG; ++g)
                if (!((keep >> g) & 1u) && gs[g] > best) { best = gs[g]; bg = g; }
            keep |= 1u << bg;
        }

        // top-8 experts over kept groups by biased f32 score
        float wv[TOPKN]; int iv[TOPKN];
        for (int r = 0; r < TOPKN; ++r) {
            float best = -3.0e38f; int bi = 0;
            for (int g = 0; g < NG; ++g) {
                if (!((keep >> g) & 1u)) continue;
                for (int j = 0; j < GSZ; ++j) {
                    const int e = g * GSZ + j;
                    const float v = __fadd_rn(row[e], bsh[e]);
                    if (v > best) { best = v; bi = e; }
                }
            }
            wv[r] = row[bi];        // ORIGINAL (un-biased) f32 sigmoid score
            iv[r] = bi;
            row[bi] = -3.0e38f;     // -3e38 + bias stays -3e38; never re-picked
        }

        // np n=8 pairwise-sum tree, then div-then-mul (elementwise, f32)
        const float s01 = __fadd_rn(wv[0], wv[1]);
        const float s23 = __fadd_rn(wv[2], wv[3]);
        const float s45 = __fadd_rn(wv[4], wv[5]);
        const float s67 = __fadd_rn(wv[6], wv[7]);
        const float wsum = __fadd_rn(__fadd_rn(s01, s23), __fadd_rn(s45, s67));

        const long token = m_blk + tid;
#pragma unroll
        for (int r = 0; r < TOPKN; ++r) {
            out_w[token * 8 + r] = __fmul_rn(__fdiv_rn(wv[r], wsum), 2.5f);
            out_i[token * 8 + r] = (float)iv[r];
        }
    }
}

extern "C" void kernel_launch(void* const* d_in, const int* in_sizes, int n_in,
                              void* d_out, int out_size, void* d_ws, size_t ws_size,
                              hipStream_t stream)
{
    const float* x    = (const float*)d_in[0];
    const float* w    = (const float*)d_in[1];
    const float* bias = (const float*)d_in[2];
    float* out = (float*)d_out;
    const int T = in_sizes[0] / DIM_K;      // 16384

    gemm_sigmoid_route<<<dim3(T / BM), dim3(256), 0, stream>>>(
        x, w, bias, out, out + (long)T * TOPKN);
}

// Round 4
// 1534.365 us; speedup vs baseline: 1.3702x; 1.0005x over previous
//
#include <hip/hip_runtime.h>
#include <math.h>

#define DIM_K 7168
#define NE 256
#define NG 8
#define GSZ 32
#define TOPKN 8
#define TOPKG 4

constexpr int BM = 32;      // tokens per block
constexpr int BK = 16;      // k-chunk
constexpr int NCH = DIM_K / BK;  // 448 chunks
constexpr int LDK = BK + 4; // LDS row stride (f32): 20 keeps float4 16B-alignment
                            // and spreads banks (gcd(20,32)=4 -> <=2 lanes/bank)

typedef __attribute__((ext_vector_type(4))) double dbl4;

// LDS: GEMM phase uses TWO buffers of (As[BM][LDK] + Bs[NE][LDK]) = 2*23040 B
// (double-buffered, ONE barrier per chunk). Route phase (after final barrier,
// all GEMM buffers dead) reuses the bytes as sc[BM][NE+1] + bsh[NE] = 33920 B.
constexpr int ABYTES = BM * LDK * 4;          // 2560
constexpr int BBYTES = NE * LDK * 4;          // 20480
constexpr int BUFB   = ABYTES + BBYTES;       // 23040 per buffer
constexpr int GEMM_BYTES  = 2 * BUFB;         // 46080
constexpr int ROUTE_BYTES = (BM * (NE + 1) + NE) * 4;  // 33920
constexpr int SMEM_BYTES  = ROUTE_BYTES > GEMM_BYTES ? ROUTE_BYTES : GEMM_BYTES;

// ---------------------------------------------------------------------------
// Fused GEMM + sigmoid + routing, double-buffered (T3-lite 2-phase).
// GEMM: f64-accumulated logits on the f64 matrix pipe, f64 sigmoid, RNE cast
// to f32 (numerics identical to the passing R2/R3 kernels).
// FRAGMENT LAYOUTS for v_mfma_f64_16x16x4_f64:
//   A[i][k]: i = lane&15, k = lane>>4
//   B[k][j]: j = lane&15, k = lane>>4
//   C/D[i][j]: j = lane&15, i = 4*reg + (lane>>4)   <-- REGISTER-MAJOR (f64
//   quirk, verified R2; standard 16x16 mapping is 4*(lane>>4)+reg).
// Schedule: per chunk, {MFMA cluster from buf | ds_write next chunk to buf^1 |
// global prefetch chunk+2} then ONE __syncthreads. Writes target the buffer
// no wave reads this iteration (prev readers drained by prev barrier), so
// staging overlaps the matrix pipe instead of serializing behind 2 barriers.
// ---------------------------------------------------------------------------
__global__ __launch_bounds__(256, 2)
void gemm_sigmoid_route(const float* __restrict__ x,
                        const float* __restrict__ w,
                        const float* __restrict__ bias,
                        float* __restrict__ out_w,
                        float* __restrict__ out_i)
{
    __shared__ __align__(16) char smem[SMEM_BYTES];

    const int tid  = threadIdx.x;
    const int wave = tid >> 6;
    const int lane = tid & 63;
    const int m_blk = blockIdx.x * BM;

    const int l15 = lane & 15;
    const int lk  = lane >> 4;        // k-offset inside one mfma / row sub-idx
    const int e_base = wave * 64;     // wave's 64-expert slice

    const dbl4 zero = {0.0, 0.0, 0.0, 0.0};
    dbl4 acc[2][4];                   // [m-subtile][e-subtile], 64 VGPRs
#pragma unroll
    for (int i = 0; i < 2; ++i)
#pragma unroll
        for (int j = 0; j < 4; ++j) acc[i][j] = zero;

    // staging: A 32x16 f32 (128 float4, threads<128) + B 256x16 f32 (4 float4
    // per thread). Row-major in LDS -> float4 load + b128 write, no transpose.
    const int srow = tid >> 2;        // 0..63
    const int sc4  = (tid & 3) * 4;   // f32 col within chunk

    const float* xa = x + (long)(m_blk + (srow & 31)) * DIM_K + sc4;
    const float* wb = w + (long)srow * DIM_K + sc4;

    float (*Ar)[LDK] = (float (*)[LDK])(smem);                  // read buf
    float (*Br)[LDK] = (float (*)[LDK])(smem + ABYTES);
    float (*Aw)[LDK] = (float (*)[LDK])(smem + BUFB);           // write buf
    float (*Bw)[LDK] = (float (*)[LDK])(smem + BUFB + ABYTES);

    float4 ra, rb0, rb1, rb2, rb3;

    // prologue: chunk 0 -> regs -> buf0; chunk 1 -> regs; barrier.
    if (tid < 128) ra = *(const float4*)xa;
    rb0 = *(const float4*)(wb);
    rb1 = *(const float4*)(wb + (long) 64 * DIM_K);
    rb2 = *(const float4*)(wb + (long)128 * DIM_K);
    rb3 = *(const float4*)(wb + (long)192 * DIM_K);
    if (tid < 128) *(float4*)&Ar[srow & 31][sc4] = ra;
    *(float4*)&Br[srow      ][sc4] = rb0;
    *(float4*)&Br[srow +  64][sc4] = rb1;
    *(float4*)&Br[srow + 128][sc4] = rb2;
    *(float4*)&Br[srow + 192][sc4] = rb3;
    if (tid < 128) ra = *(const float4*)(xa + BK);
    rb0 = *(const float4*)(wb + BK);
    rb1 = *(const float4*)(wb + BK + (long) 64 * DIM_K);
    rb2 = *(const float4*)(wb + BK + (long)128 * DIM_K);
    rb3 = *(const float4*)(wb + BK + (long)192 * DIM_K);
    __syncthreads();

    for (int t = 0; t < NCH; ++t) {
        // MFMA cluster from read buffer
#pragma unroll
        for (int ks = 0; ks < BK; ks += 4) {
            const int kk = ks + lk;
            const double a0 = (double)Ar[l15     ][kk];
            const double a1 = (double)Ar[l15 + 16][kk];
            const double b0 = (double)Br[e_base      + l15][kk];
            const double b1 = (double)Br[e_base + 16 + l15][kk];
            const double b2 = (double)Br[e_base + 32 + l15][kk];
            const double b3 = (double)Br[e_base + 48 + l15][kk];
            acc[0][0] = __builtin_amdgcn_mfma_f64_16x16x4f64(a0, b0, acc[0][0], 0, 0, 0);
            acc[1][0] = __builtin_amdgcn_mfma_f64_16x16x4f64(a1, b0, acc[1][0], 0, 0, 0);
            acc[0][1] = __builtin_amdgcn_mfma_f64_16x16x4f64(a0, b1, acc[0][1], 0, 0, 0);
            acc[1][1] = __builtin_amdgcn_mfma_f64_16x16x4f64(a1, b1, acc[1][1], 0, 0, 0);
            acc[0][2] = __builtin_amdgcn_mfma_f64_16x16x4f64(a0, b2, acc[0][2], 0, 0, 0);
            acc[1][2] = __builtin_amdgcn_mfma_f64_16x16x4f64(a1, b2, acc[1][2], 0, 0, 0);
            acc[0][3] = __builtin_amdgcn_mfma_f64_16x16x4f64(a0, b3, acc[0][3], 0, 0, 0);
            acc[1][3] = __builtin_amdgcn_mfma_f64_16x16x4f64(a1, b3, acc[1][3], 0, 0, 0);
        }

        // stage chunk t+1 into the buffer nobody reads this iteration;
        // prefetch chunk t+2 into the freed registers.
        if (t + 1 < NCH) {
            if (tid < 128) *(float4*)&Aw[srow & 31][sc4] = ra;
            *(float4*)&Bw[srow      ][sc4] = rb0;
            *(float4*)&Bw[srow +  64][sc4] = rb1;
            *(float4*)&Bw[srow + 128][sc4] = rb2;
            *(float4*)&Bw[srow + 192][sc4] = rb3;
            if (t + 2 < NCH) {
                const int off = (t + 2) * BK;
                if (tid < 128) ra = *(const float4*)(xa + off);
                rb0 = *(const float4*)(wb + off);
                rb1 = *(const float4*)(wb + off + (long) 64 * DIM_K);
                rb2 = *(const float4*)(wb + off + (long)128 * DIM_K);
                rb3 = *(const float4*)(wb + off + (long)192 * DIM_K);
            }
        }
        __syncthreads();

        // swap read/write buffers
        float (*tp)[LDK];
        tp = Ar; Ar = Aw; Aw = tp;
        tp = Br; Br = Bw; Bw = tp;
    }
    // All GEMM buffers dead -> repurpose LDS for routing.

    float (*sc)[NE + 1] = (float (*)[NE + 1])smem;                // [BM][257]
    float* bsh = (float*)(smem + BM * (NE + 1) * 4);              // [NE]

    // f64 sigmoid, RNE cast to f32, scattered to LDS score rows.
    // f64-MFMA C/D row mapping: row = 4*reg + (lane>>4)  (register-major).
#pragma unroll
    for (int mi = 0; mi < 2; ++mi) {
#pragma unroll
        for (int j = 0; j < 4; ++j) {
#pragma unroll
            for (int r = 0; r < 4; ++r) {
                const int m = mi * 16 + r * 4 + lk;
                const int e = e_base + j * 16 + l15;
                sc[m][e] = (float)(1.0 / (1.0 + exp(-acc[mi][j][r])));
            }
        }
    }
    if (tid < 64) {
        const float4 bv = *(const float4*)(bias + tid * 4);
        bsh[tid * 4 + 0] = bv.x;
        bsh[tid * 4 + 1] = bv.y;
        bsh[tid * 4 + 2] = bv.z;
        bsh[tid * 4 + 3] = bv.w;
    }
    __syncthreads();

    // np-faithful f32 routing, one thread per token (threads 0..31).
    // Identical scan order / __fadd_rn semantics to the passing route_f32.
    if (tid < BM) {
        float* row = sc[tid];

        // group score = top-2 sum of biased scores (f32 add, m1+m2 order = np)
        float gs[NG];
#pragma unroll
        for (int g = 0; g < NG; ++g) {
            float m1 = -3.0e38f, m2 = -3.0e38f;
            for (int j = 0; j < GSZ; ++j) {
                const int e = g * GSZ + j;
                const float v = __fadd_rn(row[e], bsh[e]);
                if (v > m1) { m2 = m1; m1 = v; }
                else if (v > m2) { m2 = v; }
            }
            gs[g] = __fadd_rn(m1, m2);
        }

        // top-4 groups (selection set only)
        unsigned keep = 0;
#pragma unroll
        for (int r = 0; r < TOPKG; ++r) {
            float best = -3.0e38f; int bg = 0;
            for (int g = 0; g < NG; ++g)
                if (!((keep >> g) & 1u) && gs[g] > best) { best = gs[g]; bg = g; }
            keep |= 1u << bg;
        }

        // top-8 experts over kept groups by biased f32 score
        float wv[TOPKN]; int iv[TOPKN];
        for (int r = 0; r < TOPKN; ++r) {
            float best = -3.0e38f; int bi = 0;
            for (int g = 0; g < NG; ++g) {
                if (!((keep >> g) & 1u)) continue;
                for (int j = 0; j < GSZ; ++j) {
                    const int e = g * GSZ + j;
                    const float v = __fadd_rn(row[e], bsh[e]);
                    if (v > best) { best = v; bi = e; }
                }
            }
            wv[r] = row[bi];        // ORIGINAL (un-biased) f32 sigmoid score
            iv[r] = bi;
            row[bi] = -3.0e38f;     // -3e38 + bias stays -3e38; never re-picked
        }

        // np n=8 pairwise-sum tree, then div-then-mul (elementwise, f32)
        const float s01 = __fadd_rn(wv[0], wv[1]);
        const float s23 = __fadd_rn(wv[2], wv[3]);
        const float s45 = __fadd_rn(wv[4], wv[5]);
        const float s67 = __fadd_rn(wv[6], wv[7]);
        const float wsum = __fadd_rn(__fadd_rn(s01, s23), __fadd_rn(s45, s67));

        const long token = m_blk + tid;
#pragma unroll
        for (int r = 0; r < TOPKN; ++r) {
            out_w[token * 8 + r] = __fmul_rn(__fdiv_rn(wv[r], wsum), 2.5f);
            out_i[token * 8 + r] = (float)iv[r];
        }
    }
}

extern "C" void kernel_launch(void* const* d_in, const int* in_sizes, int n_in,
                              void* d_out, int out_size, void* d_ws, size_t ws_size,
                              hipStream_t stream)
{
    const float* x    = (const float*)d_in[0];
    const float* w    = (const float*)d_in[1];
    const float* bias = (const float*)d_in[2];
    float* out = (float*)d_out;
    const int T = in_sizes[0] / DIM_K;      // 16384

    gemm_sigmoid_route<<<dim3(T / BM), dim3(256), 0, stream>>>(
        x, w, bias, out, out + (long)T * TOPKN);
}